// Round 1
// baseline (2089.965 us; speedup 1.0000x reference)
//
#include <hip/hip_runtime.h>

// ---------------------------------------------------------------------------
// GNN policy: 2x GCNConv (N=100k, H=64) + per-edge MLP (132->64->1), fp32.
// Strategy: device-built CSR (count/scan/fill) for deterministic-ish
// wave-per-node aggregation; edge MLP thread-per-edge with z[64] in VGPRs and
// wave-uniform weight loads (s_load scalarization) so inner loop is pure FMA.
// ---------------------------------------------------------------------------

#define HDIM 64

__global__ void count_k(const int* __restrict__ dst, int* __restrict__ cnt, int E) {
    int e = blockIdx.x * 256 + threadIdx.x;
    if (e < E) atomicAdd(&cnt[dst[e]], 1);
}

__global__ void dis_k(const int* __restrict__ cnt, float* __restrict__ dis, int N) {
    int i = blockIdx.x * 256 + threadIdx.x;
    if (i < N) dis[i] = rsqrtf((float)(cnt[i] + 1));  // +1 self-loop; deg>=1 always
}

// exclusive scan of cnt -> rowptr, chunk=1024 per block (256 thr x 4 elems)
__global__ void scan1_k(const int* __restrict__ cnt, int* __restrict__ excl,
                        int* __restrict__ bsum, int N) {
    __shared__ int wtot[4];
    int t = threadIdx.x;
    int base = blockIdx.x * 1024 + t * 4;
    int v0 = 0, v1 = 0, v2 = 0, v3 = 0;
    if (base + 3 < N) {
        int4 v = *(const int4*)(cnt + base);
        v0 = v.x; v1 = v.y; v2 = v.z; v3 = v.w;
    } else {
        if (base + 0 < N) v0 = cnt[base + 0];
        if (base + 1 < N) v1 = cnt[base + 1];
        if (base + 2 < N) v2 = cnt[base + 2];
        if (base + 3 < N) v3 = cnt[base + 3];
    }
    int ts = v0 + v1 + v2 + v3;
    int lane = t & 63, wid = t >> 6;
    int val = ts;
    #pragma unroll
    for (int d = 1; d < 64; d <<= 1) {
        int n = __shfl_up(val, d, 64);
        if (lane >= d) val += n;
    }
    if (lane == 63) wtot[wid] = val;
    __syncthreads();
    int woff = 0;
    #pragma unroll
    for (int w = 0; w < 4; w++) if (w < wid) woff += wtot[w];
    int et = woff + val - ts;   // exclusive prefix for this thread's first elem
    if (base + 0 < N) excl[base + 0] = et;
    if (base + 1 < N) excl[base + 1] = et + v0;
    if (base + 2 < N) excl[base + 2] = et + v0 + v1;
    if (base + 3 < N) excl[base + 3] = et + v0 + v1 + v2;
    if (t == 255) bsum[blockIdx.x] = woff + val;  // block total
}

// exclusive scan of block sums in-place; nb <= 256
__global__ void scan2_k(int* __restrict__ bsum, int nb) {
    __shared__ int wtot[4];
    int t = threadIdx.x;
    int v = (t < nb) ? bsum[t] : 0;
    int lane = t & 63, wid = t >> 6;
    int val = v;
    #pragma unroll
    for (int d = 1; d < 64; d <<= 1) {
        int n = __shfl_up(val, d, 64);
        if (lane >= d) val += n;
    }
    if (lane == 63) wtot[wid] = val;
    __syncthreads();
    int woff = 0;
    #pragma unroll
    for (int w = 0; w < 4; w++) if (w < wid) woff += wtot[w];
    if (t < nb) bsum[t] = woff + val - v;
}

__global__ void scan3_k(int* __restrict__ rowptr, const int* __restrict__ bsum,
                        int N, int E) {
    int t = threadIdx.x;
    int base = blockIdx.x * 1024 + t * 4;
    int off = bsum[blockIdx.x];
    #pragma unroll
    for (int j = 0; j < 4; j++) {
        int i = base + j;
        if (i < N) rowptr[i] += off;
    }
    if (blockIdx.x == 0 && t == 0) rowptr[N] = E;
}

__global__ void fill_k(const int* __restrict__ src, const int* __restrict__ dst,
                       const int* __restrict__ rowptr, int* __restrict__ fill,
                       const float* __restrict__ dis, int* __restrict__ csrc,
                       float* __restrict__ cnorm, int E) {
    int e = blockIdx.x * 256 + threadIdx.x;
    if (e >= E) return;
    int s = src[e], d = dst[e];
    int p = rowptr[d] + atomicAdd(&fill[d], 1);
    csrc[p] = s;
    cnorm[p] = dis[s] * dis[d];
}

// h0 = x @ W1   (N x 4) @ (4 x 64)
__global__ void xw1_k(const float* __restrict__ x, const float* __restrict__ W1,
                      float* __restrict__ h0, int N) {
    int gid = blockIdx.x * 256 + threadIdx.x;
    if (gid >= N * HDIM) return;
    int i = gid >> 6, f = gid & 63;
    float4 xv = *(const float4*)(x + i * 4);
    float acc = xv.x * W1[f] + xv.y * W1[64 + f] + xv.z * W1[128 + f] + xv.w * W1[192 + f];
    h0[gid] = acc;
}

// out[i,f] = relu( sum_{e in CSR[i]} hin[src_e,f]*norm_e + hin[i,f]*dis_i^2 + bias[f] )
__global__ void agg_k(const float* __restrict__ hin, float* __restrict__ hout,
                      const int* __restrict__ rowptr, const int* __restrict__ csrc,
                      const float* __restrict__ cnorm, const float* __restrict__ dis,
                      const float* __restrict__ bias, int N) {
    int wid = threadIdx.x >> 6, lane = threadIdx.x & 63;
    int i = blockIdx.x * 4 + wid;
    if (i >= N) return;
    int beg = rowptr[i], end = rowptr[i + 1];
    float acc = 0.f;
    for (int e = beg; e < end; e++) {
        int s = csrc[e];          // wave-uniform address
        float nr = cnorm[e];
        acc = fmaf(hin[s * HDIM + lane], nr, acc);   // coalesced 256B row gather
    }
    float di = dis[i];
    acc = fmaf(hin[i * HDIM + lane], di * di, acc);  // self-loop
    acc += bias[lane];
    hout[i * HDIM + lane] = fmaxf(acc, 0.f);
}

// g = h @ W2   (N x 64) @ (64 x 64), W2 staged in LDS
__global__ void gemm64_k(const float* __restrict__ hin, const float* __restrict__ W2,
                         float* __restrict__ gout, int N) {
    __shared__ float w[64 * 64];
    int t = threadIdx.x;
    for (int j = t; j < 64 * 64; j += 256) w[j] = W2[j];
    __syncthreads();
    int gid = blockIdx.x * 256 + t;
    if (gid >= N * HDIM) return;
    int i = gid >> 6, f = gid & 63;
    const float* hr = hin + i * HDIM;
    float acc = 0.f;
    #pragma unroll 8
    for (int k = 0; k < 64; k++) acc = fmaf(hr[k], w[k * 64 + f], acc);
    gout[gid] = acc;
}

__device__ __forceinline__ void fma_block(float z[64], float4 v,
                                          const float* __restrict__ w) {
    #pragma unroll
    for (int f = 0; f < 64; f++) z[f] = fmaf(v.x, w[f], z[f]);
    #pragma unroll
    for (int f = 0; f < 64; f++) z[f] = fmaf(v.y, w[64 + f], z[f]);
    #pragma unroll
    for (int f = 0; f < 64; f++) z[f] = fmaf(v.z, w[128 + f], z[f]);
    #pragma unroll
    for (int f = 0; f < 64; f++) z[f] = fmaf(v.w, w[192 + f], z[f]);
}

// per-edge: z = relu([h[s], h[d], ea] @ Wm1 + bm1); out = z @ Wm2 + bm2
__global__ void __launch_bounds__(256) edgemlp_k(
    const int* __restrict__ src, const int* __restrict__ dst,
    const float* __restrict__ ea, const float* __restrict__ h2,
    const float* __restrict__ Wm1, const float* __restrict__ bm1,
    const float* __restrict__ Wm2, const float* __restrict__ bm2,
    float* __restrict__ out, int E) {
    int e = blockIdx.x * 256 + threadIdx.x;
    if (e >= E) return;
    int s = src[e], d = dst[e];
    const float* hs = h2 + (size_t)s * HDIM;
    const float* hd = h2 + (size_t)d * HDIM;
    float z[64];
    #pragma unroll
    for (int f = 0; f < 64; f++) z[f] = bm1[f];   // uniform -> s_load
    #pragma unroll 1
    for (int k = 0; k < 64; k += 4) {
        float4 v = *(const float4*)(hs + k);
        fma_block(z, v, Wm1 + k * 64);
    }
    #pragma unroll 1
    for (int k = 0; k < 64; k += 4) {
        float4 v = *(const float4*)(hd + k);
        fma_block(z, v, Wm1 + (64 + k) * 64);
    }
    {
        float4 v = *(const float4*)(ea + (size_t)e * 4);
        fma_block(z, v, Wm1 + 128 * 64);
    }
    float acc = bm2[0];
    #pragma unroll
    for (int f = 0; f < 64; f++) acc = fmaf(fmaxf(z[f], 0.f), Wm2[f], acc);
    out[e] = acc;
}

extern "C" void kernel_launch(void* const* d_in, const int* in_sizes, int n_in,
                              void* d_out, int out_size, void* d_ws, size_t ws_size,
                              hipStream_t stream) {
    const float* x   = (const float*)d_in[0];
    const int*   ei  = (const int*)d_in[1];
    const float* ea  = (const float*)d_in[2];
    const float* W1  = (const float*)d_in[3];
    const float* b1  = (const float*)d_in[4];
    const float* W2  = (const float*)d_in[5];
    const float* b2  = (const float*)d_in[6];
    const float* Wm1 = (const float*)d_in[7];
    const float* bm1 = (const float*)d_in[8];
    const float* Wm2 = (const float*)d_in[9];
    const float* bm2 = (const float*)d_in[10];
    float* out = (float*)d_out;

    int N = in_sizes[0] / 4;    // 100000
    int E = in_sizes[1] / 2;    // 3200000
    const int* src = ei;
    const int* dst = ei + E;

    // workspace carve-out (256B aligned): ~78 MB total
    char* wp = (char*)d_ws;
    auto carve = [&](size_t bytes) -> void* {
        void* p = (void*)wp;
        wp += (bytes + 255) & ~(size_t)255;
        return p;
    };
    int*   cnt    = (int*)carve((size_t)N * 4);
    int*   rowptr = (int*)carve((size_t)(N + 1) * 4);
    int*   fillc  = (int*)carve((size_t)N * 4);
    float* dis    = (float*)carve((size_t)N * 4);
    int*   bsum   = (int*)carve(1024 * 4);
    int*   csrc   = (int*)carve((size_t)E * 4);
    float* cnorm  = (float*)carve((size_t)E * 4);
    float* B0     = (float*)carve((size_t)N * HDIM * 4);
    float* B1     = (float*)carve((size_t)N * HDIM * 4);

    hipMemsetAsync(cnt, 0, (size_t)N * 4, stream);
    hipMemsetAsync(fillc, 0, (size_t)N * 4, stream);

    int eb = (E + 255) / 256;
    int sb = (N + 1023) / 1024;   // 98 blocks

    count_k<<<eb, 256, 0, stream>>>(dst, cnt, E);
    dis_k<<<(N + 255) / 256, 256, 0, stream>>>(cnt, dis, N);
    scan1_k<<<sb, 256, 0, stream>>>(cnt, rowptr, bsum, N);
    scan2_k<<<1, 256, 0, stream>>>(bsum, sb);
    scan3_k<<<sb, 256, 0, stream>>>(rowptr, bsum, N, E);
    fill_k<<<eb, 256, 0, stream>>>(src, dst, rowptr, fillc, dis, csrc, cnorm, E);

    xw1_k<<<(N * HDIM + 255) / 256, 256, 0, stream>>>(x, W1, B0, N);
    agg_k<<<(N + 3) / 4, 256, 0, stream>>>(B0, B1, rowptr, csrc, cnorm, dis, b1, N);
    gemm64_k<<<(N * HDIM + 255) / 256, 256, 0, stream>>>(B1, W2, B0, N);
    agg_k<<<(N + 3) / 4, 256, 0, stream>>>(B0, B1, rowptr, csrc, cnorm, dis, b2, N);
    edgemlp_k<<<eb, 256, 0, stream>>>(src, dst, ea, B1, Wm1, bm1, Wm2, bm2, out, E);
}

// Round 3
// 1623.471 us; speedup vs baseline: 1.2873x; 1.2873x over previous
//
#include <hip/hip_runtime.h>

// ---------------------------------------------------------------------------
// GNN policy: 2x GCNConv (N=100k, H=64) + per-edge MLP (132->64->1).
// Edge MLP as split-bf16 MFMA GEMM (A_hi*B_hi + A_lo*B_hi + A_hi*B_lo ~= fp32).
// R2 bug fix: waves each compute a 16-col partial of the Wm2 dot; now reduced
// across waves via LDS part[4][32] (+1 syncthreads) instead of racing on out[].
// ---------------------------------------------------------------------------

#define HDIM 64
#define ME 32      // edges per tile
#define KP 136     // padded K stride (bf16 elems); 272B row -> conflict-free b128

typedef __attribute__((ext_vector_type(8))) short s16x8;
typedef __attribute__((ext_vector_type(4))) float f32x4;

__device__ __forceinline__ unsigned short bf_hi(float x) {
    unsigned u = __builtin_bit_cast(unsigned, x);
    unsigned r = (u + 0x7fffu + ((u >> 16) & 1u)) >> 16;   // RNE
    return (unsigned short)r;
}
__device__ __forceinline__ float bf_f(unsigned short h) {
    unsigned u = ((unsigned)h) << 16;
    return __builtin_bit_cast(float, u);
}

__device__ __forceinline__ void stage4(unsigned short* Ah, unsigned short* Al,
                                       int el, int k, float4 v) {
    unsigned short h0 = bf_hi(v.x), h1 = bf_hi(v.y), h2 = bf_hi(v.z), h3 = bf_hi(v.w);
    unsigned short l0 = bf_hi(v.x - bf_f(h0)), l1 = bf_hi(v.y - bf_f(h1));
    unsigned short l2 = bf_hi(v.z - bf_f(h2)), l3 = bf_hi(v.w - bf_f(h3));
    uint2 ph = make_uint2((unsigned)h0 | ((unsigned)h1 << 16),
                          (unsigned)h2 | ((unsigned)h3 << 16));
    uint2 pl = make_uint2((unsigned)l0 | ((unsigned)l1 << 16),
                          (unsigned)l2 | ((unsigned)l3 << 16));
    *(uint2*)(&Ah[el * KP + k]) = ph;
    *(uint2*)(&Al[el * KP + k]) = pl;
}

// ---------------- CSR build ----------------

__global__ void count_k(const int* __restrict__ dst, int* __restrict__ cnt, int E) {
    int e = blockIdx.x * 256 + threadIdx.x;
    if (e < E) atomicAdd(&cnt[dst[e]], 1);
}

__global__ void dis_k(const int* __restrict__ cnt, float* __restrict__ dis, int N) {
    int i = blockIdx.x * 256 + threadIdx.x;
    if (i < N) dis[i] = rsqrtf((float)(cnt[i] + 1));
}

__global__ void scan1_k(const int* __restrict__ cnt, int* __restrict__ excl,
                        int* __restrict__ bsum, int N) {
    __shared__ int wtot[4];
    int t = threadIdx.x;
    int base = blockIdx.x * 1024 + t * 4;
    int v0 = 0, v1 = 0, v2 = 0, v3 = 0;
    if (base + 3 < N) {
        int4 v = *(const int4*)(cnt + base);
        v0 = v.x; v1 = v.y; v2 = v.z; v3 = v.w;
    } else {
        if (base + 0 < N) v0 = cnt[base + 0];
        if (base + 1 < N) v1 = cnt[base + 1];
        if (base + 2 < N) v2 = cnt[base + 2];
        if (base + 3 < N) v3 = cnt[base + 3];
    }
    int ts = v0 + v1 + v2 + v3;
    int lane = t & 63, wid = t >> 6;
    int val = ts;
    #pragma unroll
    for (int d = 1; d < 64; d <<= 1) {
        int n = __shfl_up(val, d, 64);
        if (lane >= d) val += n;
    }
    if (lane == 63) wtot[wid] = val;
    __syncthreads();
    int woff = 0;
    #pragma unroll
    for (int w = 0; w < 4; w++) if (w < wid) woff += wtot[w];
    int et = woff + val - ts;
    if (base + 0 < N) excl[base + 0] = et;
    if (base + 1 < N) excl[base + 1] = et + v0;
    if (base + 2 < N) excl[base + 2] = et + v0 + v1;
    if (base + 3 < N) excl[base + 3] = et + v0 + v1 + v2;
    if (t == 255) bsum[blockIdx.x] = woff + val;
}

__global__ void scan2_k(int* __restrict__ bsum, int nb) {
    __shared__ int wtot[4];
    int t = threadIdx.x;
    int v = (t < nb) ? bsum[t] : 0;
    int lane = t & 63, wid = t >> 6;
    int val = v;
    #pragma unroll
    for (int d = 1; d < 64; d <<= 1) {
        int n = __shfl_up(val, d, 64);
        if (lane >= d) val += n;
    }
    if (lane == 63) wtot[wid] = val;
    __syncthreads();
    int woff = 0;
    #pragma unroll
    for (int w = 0; w < 4; w++) if (w < wid) woff += wtot[w];
    if (t < nb) bsum[t] = woff + val - v;
}

__global__ void scan3_k(int* __restrict__ rowptr, const int* __restrict__ bsum,
                        int N, int E) {
    int t = threadIdx.x;
    int base = blockIdx.x * 1024 + t * 4;
    int off = bsum[blockIdx.x];
    #pragma unroll
    for (int j = 0; j < 4; j++) {
        int i = base + j;
        if (i < N) rowptr[i] += off;
    }
    if (blockIdx.x == 0 && t == 0) rowptr[N] = E;
}

__global__ void fill_k(const int* __restrict__ src, const int* __restrict__ dst,
                       const int* __restrict__ rowptr, int* __restrict__ fill,
                       const float* __restrict__ dis, int* __restrict__ csrc,
                       float* __restrict__ cnorm, int E) {
    int e = blockIdx.x * 256 + threadIdx.x;
    if (e >= E) return;
    int s = src[e], d = dst[e];
    int p = rowptr[d] + atomicAdd(&fill[d], 1);
    csrc[p] = s;
    cnorm[p] = dis[s] * dis[d];
}

// ---------------- GCN layers ----------------

__global__ void xw1_k(const float* __restrict__ x, const float* __restrict__ W1,
                      float* __restrict__ h0, int N) {
    int gid = blockIdx.x * 256 + threadIdx.x;
    if (gid >= N * HDIM) return;
    int i = gid >> 6, f = gid & 63;
    float4 xv = *(const float4*)(x + i * 4);
    float acc = xv.x * W1[f] + xv.y * W1[64 + f] + xv.z * W1[128 + f] + xv.w * W1[192 + f];
    h0[gid] = acc;
}

__global__ void agg_k(const float* __restrict__ hin, float* __restrict__ hout,
                      const int* __restrict__ rowptr, const int* __restrict__ csrc,
                      const float* __restrict__ cnorm, const float* __restrict__ dis,
                      const float* __restrict__ bias, int N) {
    int wid = threadIdx.x >> 6, lane = threadIdx.x & 63;
    int i = blockIdx.x * 4 + wid;
    if (i >= N) return;
    int beg = rowptr[i], end = rowptr[i + 1];
    float acc = 0.f;
    for (int e = beg; e < end; e++) {
        int s = csrc[e];
        float nr = cnorm[e];
        acc = fmaf(hin[s * HDIM + lane], nr, acc);
    }
    float di = dis[i];
    acc = fmaf(hin[i * HDIM + lane], di * di, acc);
    acc += bias[lane];
    hout[i * HDIM + lane] = fmaxf(acc, 0.f);
}

__global__ void gemm64_k(const float* __restrict__ hin, const float* __restrict__ W2,
                         float* __restrict__ gout, int N) {
    __shared__ float w[64 * 64];
    int t = threadIdx.x;
    for (int j = t; j < 64 * 64; j += 256) w[j] = W2[j];
    __syncthreads();
    int gid = blockIdx.x * 256 + t;
    if (gid >= N * HDIM) return;
    int i = gid >> 6, f = gid & 63;
    const float* hr = hin + i * HDIM;
    float acc = 0.f;
    #pragma unroll 8
    for (int k = 0; k < 64; k++) acc = fmaf(hr[k], w[k * 64 + f], acc);
    gout[gid] = acc;
}

// ---------------- Edge MLP via split-bf16 MFMA ----------------
__global__ void __launch_bounds__(256) edgemlp_mfma_k(
    const int* __restrict__ src, const int* __restrict__ dst,
    const float* __restrict__ ea, const float* __restrict__ h2,
    const float* __restrict__ Wm1, const float* __restrict__ bm1,
    const float* __restrict__ Wm2, const float* __restrict__ bm2,
    float* __restrict__ out, int E, int ntiles)
{
    __shared__ unsigned short Bh[64 * KP];
    __shared__ unsigned short Bl[64 * KP];
    __shared__ unsigned short Ah[ME * KP];
    __shared__ unsigned short Al[ME * KP];
    __shared__ float We_s[4][64];
    __shared__ float bm1_s[64];
    __shared__ float wm2_s[64];
    __shared__ float4 ea_s[ME];
    __shared__ float part[4][ME];   // per-wave 16-col partials of the Wm2 dot

    int t = threadIdx.x;

    // stage B = Wm1[0:128,:] as bf16 hi/lo, transposed to [n][k]
    for (int i = t; i < 128 * 64; i += 256) {
        int k = i >> 6, n = i & 63;
        float w = Wm1[i];
        unsigned short h = bf_hi(w);
        Bh[n * KP + k] = h;
        Bl[n * KP + k] = bf_hi(w - bf_f(h));
    }
    {
        int j = t >> 6, n = t & 63;
        We_s[j][n] = Wm1[(128 + j) * 64 + n];
        if (t < 64) { bm1_s[t] = bm1[t]; wm2_s[t] = Wm2[t]; }
    }
    float b2v = bm2[0];

    int wid  = t >> 6;       // wave id = col-tile
    int lane = t & 63;
    int lr = lane & 15;
    int lg = lane >> 4;

    int el = t >> 3;         // staging: edge slot 0..31
    int q  = t & 7;          // staging: 16-float chunk

    for (int tile = blockIdx.x; tile < ntiles; tile += gridDim.x) {
        int e0 = tile * ME;
        __syncthreads();     // prev tile fully consumed; B visible on 1st iter

        int e = e0 + el; if (e >= E) e = E - 1;
        int s = src[e], d = dst[e];
        const float4* hs4 = (const float4*)(h2 + (size_t)s * HDIM);
        const float4* hd4 = (const float4*)(h2 + (size_t)d * HDIM);
        float4 v0 = hs4[q], v1 = hs4[q + 8], v2 = hd4[q], v3 = hd4[q + 8];
        if (q == 0) ea_s[el] = *(const float4*)(ea + (size_t)e * 4);
        stage4(Ah, Al, el, q * 4,            v0);
        stage4(Ah, Al, el, (q + 8) * 4,      v1);
        stage4(Ah, Al, el, 64 + q * 4,       v2);
        stage4(Ah, Al, el, 64 + (q + 8) * 4, v3);
        __syncthreads();

        f32x4 acc0 = {0.f, 0.f, 0.f, 0.f}, acc1 = {0.f, 0.f, 0.f, 0.f};
        #pragma unroll
        for (int kt = 0; kt < 4; kt++) {
            int ko = kt * 32 + lg * 8;
            s16x8 a0h = *(const s16x8*)(&Ah[(lr)      * KP + ko]);
            s16x8 a0l = *(const s16x8*)(&Al[(lr)      * KP + ko]);
            s16x8 a1h = *(const s16x8*)(&Ah[(16 + lr) * KP + ko]);
            s16x8 a1l = *(const s16x8*)(&Al[(16 + lr) * KP + ko]);
            s16x8 bh  = *(const s16x8*)(&Bh[(wid * 16 + lr) * KP + ko]);
            s16x8 bl  = *(const s16x8*)(&Bl[(wid * 16 + lr) * KP + ko]);
            acc0 = __builtin_amdgcn_mfma_f32_16x16x32_bf16(a0h, bh, acc0, 0, 0, 0);
            acc1 = __builtin_amdgcn_mfma_f32_16x16x32_bf16(a1h, bh, acc1, 0, 0, 0);
            acc0 = __builtin_amdgcn_mfma_f32_16x16x32_bf16(a0l, bh, acc0, 0, 0, 0);
            acc1 = __builtin_amdgcn_mfma_f32_16x16x32_bf16(a1l, bh, acc1, 0, 0, 0);
            acc0 = __builtin_amdgcn_mfma_f32_16x16x32_bf16(a0h, bl, acc0, 0, 0, 0);
            acc1 = __builtin_amdgcn_mfma_f32_16x16x32_bf16(a1h, bl, acc1, 0, 0, 0);
        }

        // epilogue: + bm1 + ea@We, relu, *Wm2, reduce 16 cols -> per-wave partial
        int c = wid * 16 + lr;
        float b1c = bm1_s[c], w2c = wm2_s[c];
        float we0 = We_s[0][c], we1 = We_s[1][c], we2 = We_s[2][c], we3 = We_s[3][c];
        #pragma unroll
        for (int rt = 0; rt < 2; rt++) {
            f32x4 ac = rt ? acc1 : acc0;
            int rb = rt * 16 + lg * 4;
            float p[4];
            #pragma unroll
            for (int r = 0; r < 4; r++) {
                float4 eav = ea_s[rb + r];
                float z = ac[r] + b1c;
                z = fmaf(eav.x, we0, z); z = fmaf(eav.y, we1, z);
                z = fmaf(eav.z, we2, z); z = fmaf(eav.w, we3, z);
                z = fmaxf(z, 0.f);
                p[r] = z * w2c;
            }
            #pragma unroll
            for (int m = 1; m < 16; m <<= 1) {
                #pragma unroll
                for (int r = 0; r < 4; r++) p[r] += __shfl_xor(p[r], m, 64);
            }
            if (lr == 0) {
                #pragma unroll
                for (int r = 0; r < 4; r++) part[wid][rb + r] = p[r];
            }
        }
        __syncthreads();     // partials visible

        if (t < ME) {        // cross-wave reduce: 4 partials -> logit
            int eo = e0 + t;
            if (eo < E)
                out[eo] = part[0][t] + part[1][t] + part[2][t] + part[3][t] + b2v;
        }
        // loop-top __syncthreads protects part/Ah/Al reuse next iteration
    }
}

extern "C" void kernel_launch(void* const* d_in, const int* in_sizes, int n_in,
                              void* d_out, int out_size, void* d_ws, size_t ws_size,
                              hipStream_t stream) {
    const float* x   = (const float*)d_in[0];
    const int*   ei  = (const int*)d_in[1];
    const float* ea  = (const float*)d_in[2];
    const float* W1  = (const float*)d_in[3];
    const float* b1  = (const float*)d_in[4];
    const float* W2  = (const float*)d_in[5];
    const float* b2  = (const float*)d_in[6];
    const float* Wm1 = (const float*)d_in[7];
    const float* bm1 = (const float*)d_in[8];
    const float* Wm2 = (const float*)d_in[9];
    const float* bm2 = (const float*)d_in[10];
    float* out = (float*)d_out;

    int N = in_sizes[0] / 4;    // 100000
    int E = in_sizes[1] / 2;    // 3200000
    const int* src = ei;
    const int* dst = ei + E;

    char* wp = (char*)d_ws;
    auto carve = [&](size_t bytes) -> void* {
        void* p = (void*)wp;
        wp += (bytes + 255) & ~(size_t)255;
        return p;
    };
    int*   cnt    = (int*)carve((size_t)N * 4);
    int*   rowptr = (int*)carve((size_t)(N + 1) * 4);
    int*   fillc  = (int*)carve((size_t)N * 4);
    float* dis    = (float*)carve((size_t)N * 4);
    int*   bsum   = (int*)carve(1024 * 4);
    int*   csrc   = (int*)carve((size_t)E * 4);
    float* cnorm  = (float*)carve((size_t)E * 4);
    float* B0     = (float*)carve((size_t)N * HDIM * 4);
    float* B1     = (float*)carve((size_t)N * HDIM * 4);

    hipMemsetAsync(cnt, 0, (size_t)N * 4, stream);
    hipMemsetAsync(fillc, 0, (size_t)N * 4, stream);

    int eb = (E + 255) / 256;
    int sb = (N + 1023) / 1024;

    count_k<<<eb, 256, 0, stream>>>(dst, cnt, E);
    dis_k<<<(N + 255) / 256, 256, 0, stream>>>(cnt, dis, N);
    scan1_k<<<sb, 256, 0, stream>>>(cnt, rowptr, bsum, N);
    scan2_k<<<1, 256, 0, stream>>>(bsum, sb);
    scan3_k<<<sb, 256, 0, stream>>>(rowptr, bsum, N, E);
    fill_k<<<eb, 256, 0, stream>>>(src, dst, rowptr, fillc, dis, csrc, cnorm, E);

    xw1_k<<<(N * HDIM + 255) / 256, 256, 0, stream>>>(x, W1, B0, N);
    agg_k<<<(N + 3) / 4, 256, 0, stream>>>(B0, B1, rowptr, csrc, cnorm, dis, b1, N);
    gemm64_k<<<(N * HDIM + 255) / 256, 256, 0, stream>>>(B1, W2, B0, N);
    agg_k<<<(N + 3) / 4, 256, 0, stream>>>(B0, B1, rowptr, csrc, cnorm, dis, b2, N);

    int ntiles = (E + ME - 1) / ME;
    edgemlp_mfma_k<<<512, 256, 0, stream>>>(src, dst, ea, B1, Wm1, bm1, Wm2, bm2,
                                            out, E, ntiles);
}

// Round 5
// 1000.999 us; speedup vs baseline: 2.0879x; 1.6219x over previous
//
#include <hip/hip_runtime.h>
#include <hip/hip_fp16.h>

// ---------------------------------------------------------------------------
// GNN policy: 2x GCNConv (N=100k, H=64) + per-edge MLP (132->64->1).
// R4 (resubmit after broker timeout): edge MLP factored per-node:
// P = h@Wm1[0:64]+bm1, Q = h@Wm1[64:128] (fp16), so each edge is
// gather(P[s])+gather(Q[d])+ea@We -> relu -> dot Wm2. 34x less FLOP than the
// per-edge GEMM; memory-bound gather with weights in VGPRs. CSR aggregation:
// packed (src,norm) int2 + 4-deep unrolled gather.
// ---------------------------------------------------------------------------

#define HDIM 64

// ---------------- CSR build ----------------

__global__ void count_k(const int* __restrict__ dst, int* __restrict__ cnt, int E) {
    int e = blockIdx.x * 256 + threadIdx.x;
    if (e < E) atomicAdd(&cnt[dst[e]], 1);
}

__global__ void dis_k(const int* __restrict__ cnt, float* __restrict__ dis, int N) {
    int i = blockIdx.x * 256 + threadIdx.x;
    if (i < N) dis[i] = rsqrtf((float)(cnt[i] + 1));  // +1 self-loop
}

__global__ void scan1_k(const int* __restrict__ cnt, int* __restrict__ excl,
                        int* __restrict__ bsum, int N) {
    __shared__ int wtot[4];
    int t = threadIdx.x;
    int base = blockIdx.x * 1024 + t * 4;
    int v0 = 0, v1 = 0, v2 = 0, v3 = 0;
    if (base + 3 < N) {
        int4 v = *(const int4*)(cnt + base);
        v0 = v.x; v1 = v.y; v2 = v.z; v3 = v.w;
    } else {
        if (base + 0 < N) v0 = cnt[base + 0];
        if (base + 1 < N) v1 = cnt[base + 1];
        if (base + 2 < N) v2 = cnt[base + 2];
        if (base + 3 < N) v3 = cnt[base + 3];
    }
    int ts = v0 + v1 + v2 + v3;
    int lane = t & 63, wid = t >> 6;
    int val = ts;
    #pragma unroll
    for (int d = 1; d < 64; d <<= 1) {
        int n = __shfl_up(val, d, 64);
        if (lane >= d) val += n;
    }
    if (lane == 63) wtot[wid] = val;
    __syncthreads();
    int woff = 0;
    #pragma unroll
    for (int w = 0; w < 4; w++) if (w < wid) woff += wtot[w];
    int et = woff + val - ts;
    if (base + 0 < N) excl[base + 0] = et;
    if (base + 1 < N) excl[base + 1] = et + v0;
    if (base + 2 < N) excl[base + 2] = et + v0 + v1;
    if (base + 3 < N) excl[base + 3] = et + v0 + v1 + v2;
    if (t == 255) bsum[blockIdx.x] = woff + val;
}

__global__ void scan2_k(int* __restrict__ bsum, int nb) {
    __shared__ int wtot[4];
    int t = threadIdx.x;
    int v = (t < nb) ? bsum[t] : 0;
    int lane = t & 63, wid = t >> 6;
    int val = v;
    #pragma unroll
    for (int d = 1; d < 64; d <<= 1) {
        int n = __shfl_up(val, d, 64);
        if (lane >= d) val += n;
    }
    if (lane == 63) wtot[wid] = val;
    __syncthreads();
    int woff = 0;
    #pragma unroll
    for (int w = 0; w < 4; w++) if (w < wid) woff += wtot[w];
    if (t < nb) bsum[t] = woff + val - v;
}

__global__ void scan3_k(int* __restrict__ rowptr, const int* __restrict__ bsum,
                        int N, int E) {
    int t = threadIdx.x;
    int base = blockIdx.x * 1024 + t * 4;
    int off = bsum[blockIdx.x];
    #pragma unroll
    for (int j = 0; j < 4; j++) {
        int i = base + j;
        if (i < N) rowptr[i] += off;
    }
    if (blockIdx.x == 0 && t == 0) rowptr[N] = E;
}

// packs (src, norm) into one int2 per CSR slot
__global__ void fill_k(const int* __restrict__ src, const int* __restrict__ dst,
                       const int* __restrict__ rowptr, int* __restrict__ fill,
                       const float* __restrict__ dis, int2* __restrict__ cpack,
                       int E) {
    int e = blockIdx.x * 256 + threadIdx.x;
    if (e >= E) return;
    int s = src[e], d = dst[e];
    int p = rowptr[d] + atomicAdd(&fill[d], 1);
    cpack[p] = make_int2(s, __float_as_int(dis[s] * dis[d]));
}

// ---------------- GCN layers ----------------

__global__ void xw1_k(const float* __restrict__ x, const float* __restrict__ W1,
                      float* __restrict__ h0, int N) {
    int gid = blockIdx.x * 256 + threadIdx.x;
    if (gid >= N * HDIM) return;
    int i = gid >> 6, f = gid & 63;
    float4 xv = *(const float4*)(x + i * 4);
    float acc = xv.x * W1[f] + xv.y * W1[64 + f] + xv.z * W1[128 + f] + xv.w * W1[192 + f];
    h0[gid] = acc;
}

__global__ void agg_k(const float* __restrict__ hin, float* __restrict__ hout,
                      const int* __restrict__ rowptr, const int2* __restrict__ cp,
                      const float* __restrict__ dis, const float* __restrict__ bias,
                      int N) {
    int wid = threadIdx.x >> 6, lane = threadIdx.x & 63;
    int i = blockIdx.x * 4 + wid;
    if (i >= N) return;
    int beg = rowptr[i], end = rowptr[i + 1];
    float acc = 0.f;
    int e = beg;
    for (; e + 4 <= end; e += 4) {      // 4-deep ILP on the row gathers
        int2 c0 = cp[e], c1 = cp[e + 1], c2 = cp[e + 2], c3 = cp[e + 3];
        float v0 = hin[(size_t)c0.x * HDIM + lane];
        float v1 = hin[(size_t)c1.x * HDIM + lane];
        float v2 = hin[(size_t)c2.x * HDIM + lane];
        float v3 = hin[(size_t)c3.x * HDIM + lane];
        acc = fmaf(v0, __int_as_float(c0.y), acc);
        acc = fmaf(v1, __int_as_float(c1.y), acc);
        acc = fmaf(v2, __int_as_float(c2.y), acc);
        acc = fmaf(v3, __int_as_float(c3.y), acc);
    }
    for (; e < end; e++) {
        int2 c = cp[e];
        acc = fmaf(hin[(size_t)c.x * HDIM + lane], __int_as_float(c.y), acc);
    }
    float di = dis[i];
    acc = fmaf(hin[(size_t)i * HDIM + lane], di * di, acc);  // self-loop
    acc += bias[lane];
    hout[(size_t)i * HDIM + lane] = fmaxf(acc, 0.f);
}

__global__ void gemm64_k(const float* __restrict__ hin, const float* __restrict__ W2,
                         float* __restrict__ gout, int N) {
    __shared__ float w[64 * 64];
    int t = threadIdx.x;
    for (int j = t; j < 64 * 64; j += 256) w[j] = W2[j];
    __syncthreads();
    int gid = blockIdx.x * 256 + t;
    if (gid >= N * HDIM) return;
    int i = gid >> 6, f = gid & 63;
    const float* hr = hin + (size_t)i * HDIM;
    float acc = 0.f;
    #pragma unroll 8
    for (int k = 0; k < 64; k++) acc = fmaf(hr[k], w[k * 64 + f], acc);
    gout[gid] = acc;
}

// ---------------- Edge-MLP factorization ----------------
// P[i][f] = sum_k h[i][k]*Wm1[k][f] + bm1[f]   (bias folded into P)
// Q[i][f] = sum_k h[i][k]*Wm1[64+k][f]
__global__ void pq_k(const float* __restrict__ h, const float* __restrict__ Wm1,
                     const float* __restrict__ bm1,
                     __half* __restrict__ Ph, __half* __restrict__ Qh, int N) {
    __shared__ float w[128 * 64];     // 32 KB: Wm1 rows 0..127
    int t = threadIdx.x;
    for (int j = t; j < 128 * 64; j += 256) w[j] = Wm1[j];
    __syncthreads();
    int gid = blockIdx.x * 256 + t;
    if (gid >= N * HDIM) return;
    int i = gid >> 6, f = gid & 63;
    const float* hr = h + (size_t)i * HDIM;
    float a = bm1[f], b = 0.f;
    #pragma unroll 8
    for (int k = 0; k < 64; k++) {
        float hv = hr[k];             // wave-uniform broadcast
        a = fmaf(hv, w[k * 64 + f], a);
        b = fmaf(hv, w[(64 + k) * 64 + f], b);
    }
    Ph[gid] = __float2half(a);
    Qh[gid] = __float2half(b);
}

// per-edge: z = relu(P[s] + Q[d] + ea@We), logit = z . Wm2 + bm2
// 8 threads per edge, 8 features each; weights in loop-invariant VGPRs.
__global__ void __launch_bounds__(256) edgefin_k(
    const int* __restrict__ src, const int* __restrict__ dst,
    const float* __restrict__ ea,
    const __half* __restrict__ Ph, const __half* __restrict__ Qh,
    const float* __restrict__ Wm1, const float* __restrict__ Wm2,
    const float* __restrict__ bm2, float* __restrict__ out, int E) {
    int q = threadIdx.x & 7;
    int fb = q * 8;
    float w2r[8];
    float wer[4][8];
    *(float4*)&w2r[0] = *(const float4*)(Wm2 + fb);
    *(float4*)&w2r[4] = *(const float4*)(Wm2 + fb + 4);
    #pragma unroll
    for (int r = 0; r < 4; r++) {
        *(float4*)&wer[r][0] = *(const float4*)(Wm1 + (128 + r) * 64 + fb);
        *(float4*)&wer[r][4] = *(const float4*)(Wm1 + (128 + r) * 64 + fb + 4);
    }
    float b2v = bm2[0];

    int gstride = gridDim.x * 32;       // 32 edges per block pass
    for (int e = blockIdx.x * 32 + (threadIdx.x >> 3); e < E; e += gstride) {
        int s = src[e], d = dst[e];
        uint4 pv = *(const uint4*)((const unsigned short*)Ph + (size_t)s * HDIM + fb);
        uint4 qv = *(const uint4*)((const unsigned short*)Qh + (size_t)d * HDIM + fb);
        float4 eav = *(const float4*)(ea + (size_t)e * 4);
        float p = 0.f;
        #pragma unroll
        for (int w = 0; w < 4; w++) {
            unsigned pu = (&pv.x)[w], qu = (&qv.x)[w];
            float2 pf = __half22float2(__builtin_bit_cast(__half2, pu));
            float2 qf = __half22float2(__builtin_bit_cast(__half2, qu));
            int j0 = 2 * w, j1 = 2 * w + 1;
            float z0 = pf.x + qf.x;
            z0 = fmaf(eav.x, wer[0][j0], z0); z0 = fmaf(eav.y, wer[1][j0], z0);
            z0 = fmaf(eav.z, wer[2][j0], z0); z0 = fmaf(eav.w, wer[3][j0], z0);
            float z1 = pf.y + qf.y;
            z1 = fmaf(eav.x, wer[0][j1], z1); z1 = fmaf(eav.y, wer[1][j1], z1);
            z1 = fmaf(eav.z, wer[2][j1], z1); z1 = fmaf(eav.w, wer[3][j1], z1);
            p = fmaf(fmaxf(z0, 0.f), w2r[j0], p);
            p = fmaf(fmaxf(z1, 0.f), w2r[j1], p);
        }
        p += __shfl_xor(p, 1, 64);
        p += __shfl_xor(p, 2, 64);
        p += __shfl_xor(p, 4, 64);
        if (q == 0) out[e] = p + b2v;
    }
}

extern "C" void kernel_launch(void* const* d_in, const int* in_sizes, int n_in,
                              void* d_out, int out_size, void* d_ws, size_t ws_size,
                              hipStream_t stream) {
    const float* x   = (const float*)d_in[0];
    const int*   ei  = (const int*)d_in[1];
    const float* ea  = (const float*)d_in[2];
    const float* W1  = (const float*)d_in[3];
    const float* b1  = (const float*)d_in[4];
    const float* W2  = (const float*)d_in[5];
    const float* b2  = (const float*)d_in[6];
    const float* Wm1 = (const float*)d_in[7];
    const float* bm1 = (const float*)d_in[8];
    const float* Wm2 = (const float*)d_in[9];
    const float* bm2 = (const float*)d_in[10];
    float* out = (float*)d_out;

    int N = in_sizes[0] / 4;    // 100000
    int E = in_sizes[1] / 2;    // 3200000
    const int* src = ei;
    const int* dst = ei + E;

    char* wp = (char*)d_ws;
    auto carve = [&](size_t bytes) -> void* {
        void* p = (void*)wp;
        wp += (bytes + 255) & ~(size_t)255;
        return p;
    };
    int*   cnt    = (int*)carve((size_t)N * 4);
    int*   rowptr = (int*)carve((size_t)(N + 1) * 4);
    int*   fillc  = (int*)carve((size_t)N * 4);
    float* dis    = (float*)carve((size_t)N * 4);
    int*   bsum   = (int*)carve(1024 * 4);
    int2*  cpack  = (int2*)carve((size_t)E * 8);
    float* B0     = (float*)carve((size_t)N * HDIM * 4);
    float* B1     = (float*)carve((size_t)N * HDIM * 4);
    // Ph/Qh overlay B0 (free after agg2 consumes it): 2 * N*64*2B = N*64*4B
    __half* Ph = (__half*)B0;
    __half* Qh = Ph + (size_t)N * HDIM;

    hipMemsetAsync(cnt, 0, (size_t)N * 4, stream);
    hipMemsetAsync(fillc, 0, (size_t)N * 4, stream);

    int eb = (E + 255) / 256;
    int sb = (N + 1023) / 1024;

    count_k<<<eb, 256, 0, stream>>>(dst, cnt, E);
    dis_k<<<(N + 255) / 256, 256, 0, stream>>>(cnt, dis, N);
    scan1_k<<<sb, 256, 0, stream>>>(cnt, rowptr, bsum, N);
    scan2_k<<<1, 256, 0, stream>>>(bsum, sb);
    scan3_k<<<sb, 256, 0, stream>>>(rowptr, bsum, N, E);
    fill_k<<<eb, 256, 0, stream>>>(src, dst, rowptr, fillc, dis, cpack, E);

    xw1_k<<<(N * HDIM + 255) / 256, 256, 0, stream>>>(x, W1, B0, N);
    agg_k<<<(N + 3) / 4, 256, 0, stream>>>(B0, B1, rowptr, cpack, dis, b1, N);
    gemm64_k<<<(N * HDIM + 255) / 256, 256, 0, stream>>>(B1, W2, B0, N);
    agg_k<<<(N + 3) / 4, 256, 0, stream>>>(B0, B1, rowptr, cpack, dis, b2, N);

    // h2 (B1) -> P,Q fp16 (overlaying B0, which is now dead)
    pq_k<<<(N * HDIM + 255) / 256, 256, 0, stream>>>(B1, Wm1, bm1, Ph, Qh, N);
    edgefin_k<<<2048, 256, 0, stream>>>(src, dst, ea, Ph, Qh, Wm1, Wm2, bm2, out, E);
}

// Round 6
// 860.007 us; speedup vs baseline: 2.4302x; 1.1639x over previous
//
#include <hip/hip_runtime.h>
#include <hip/hip_fp16.h>

// ---------------------------------------------------------------------------
// GNN policy: 2x GCNConv (N=100k, H=64) + per-edge MLP (132->64->1).
// R6: (1) layer-1 aggregation moved to x-space (agg(x)@W1 == agg(x@W1)):
// 4-dim gathers instead of 64-dim. (2) layer-2 aggregation on fp16 h1 with
// 2-edges-per-wave + 2-deep unroll. (3) edgefin processes 2 edges per 8-lane
// group for doubled memory-level parallelism. P/Q factorization as R5.
// Workspace overlays keep total at ~78.4MB (same as proven R5 footprint).
// ---------------------------------------------------------------------------

#define HDIM 64

// ---------------- CSR build ----------------

__global__ void count_k(const int* __restrict__ dst, int* __restrict__ cnt, int E) {
    int e = blockIdx.x * 256 + threadIdx.x;
    if (e < E) atomicAdd(&cnt[dst[e]], 1);
}

__global__ void dis_k(const int* __restrict__ cnt, float* __restrict__ dis, int N) {
    int i = blockIdx.x * 256 + threadIdx.x;
    if (i < N) dis[i] = rsqrtf((float)(cnt[i] + 1));  // +1 self-loop
}

__global__ void scan1_k(const int* __restrict__ cnt, int* __restrict__ excl,
                        int* __restrict__ bsum, int N) {
    __shared__ int wtot[4];
    int t = threadIdx.x;
    int base = blockIdx.x * 1024 + t * 4;
    int v0 = 0, v1 = 0, v2 = 0, v3 = 0;
    if (base + 3 < N) {
        int4 v = *(const int4*)(cnt + base);
        v0 = v.x; v1 = v.y; v2 = v.z; v3 = v.w;
    } else {
        if (base + 0 < N) v0 = cnt[base + 0];
        if (base + 1 < N) v1 = cnt[base + 1];
        if (base + 2 < N) v2 = cnt[base + 2];
        if (base + 3 < N) v3 = cnt[base + 3];
    }
    int ts = v0 + v1 + v2 + v3;
    int lane = t & 63, wid = t >> 6;
    int val = ts;
    #pragma unroll
    for (int d = 1; d < 64; d <<= 1) {
        int n = __shfl_up(val, d, 64);
        if (lane >= d) val += n;
    }
    if (lane == 63) wtot[wid] = val;
    __syncthreads();
    int woff = 0;
    #pragma unroll
    for (int w = 0; w < 4; w++) if (w < wid) woff += wtot[w];
    int et = woff + val - ts;
    if (base + 0 < N) excl[base + 0] = et;
    if (base + 1 < N) excl[base + 1] = et + v0;
    if (base + 2 < N) excl[base + 2] = et + v0 + v1;
    if (base + 3 < N) excl[base + 3] = et + v0 + v1 + v2;
    if (t == 255) bsum[blockIdx.x] = woff + val;
}

__global__ void scan2_k(int* __restrict__ bsum, int nb) {
    __shared__ int wtot[4];
    int t = threadIdx.x;
    int v = (t < nb) ? bsum[t] : 0;
    int lane = t & 63, wid = t >> 6;
    int val = v;
    #pragma unroll
    for (int d = 1; d < 64; d <<= 1) {
        int n = __shfl_up(val, d, 64);
        if (lane >= d) val += n;
    }
    if (lane == 63) wtot[wid] = val;
    __syncthreads();
    int woff = 0;
    #pragma unroll
    for (int w = 0; w < 4; w++) if (w < wid) woff += wtot[w];
    if (t < nb) bsum[t] = woff + val - v;
}

__global__ void scan3_k(int* __restrict__ rowptr, const int* __restrict__ bsum,
                        int N, int E) {
    int t = threadIdx.x;
    int base = blockIdx.x * 1024 + t * 4;
    int off = bsum[blockIdx.x];
    #pragma unroll
    for (int j = 0; j < 4; j++) {
        int i = base + j;
        if (i < N) rowptr[i] += off;
    }
    if (blockIdx.x == 0 && t == 0) rowptr[N] = E;
}

// packs (src, norm) into one int2 per CSR slot
__global__ void fill_k(const int* __restrict__ src, const int* __restrict__ dst,
                       const int* __restrict__ rowptr, int* __restrict__ fill,
                       const float* __restrict__ dis, int2* __restrict__ cpack,
                       int E) {
    int e = blockIdx.x * 256 + threadIdx.x;
    if (e >= E) return;
    int s = src[e], d = dst[e];
    int p = rowptr[d] + atomicAdd(&fill[d], 1);
    cpack[p] = make_int2(s, __float_as_int(dis[s] * dis[d]));
}

// ---------------- Layer 1: aggregate x (4-dim), then transform ----------------
// xa[i] = sum_e norm_e * x[src_e] + dis_i^2 * x[i]
__global__ void __launch_bounds__(256) aggX_k(
    const float* __restrict__ x, float* __restrict__ xa,
    const int* __restrict__ rowptr, const int2* __restrict__ cp,
    const float* __restrict__ dis, int N) {
    int t = threadIdx.x;
    int node = blockIdx.x * 64 + (t >> 2);
    int f = t & 3;
    if (node >= N) return;
    int beg = rowptr[node], end = rowptr[node + 1];
    float acc = 0.f;
    int e = beg;
    for (; e + 2 <= end; e += 2) {       // 2 gathers in flight
        int2 c0 = cp[e], c1 = cp[e + 1];
        float v0 = x[(size_t)c0.x * 4 + f];
        float v1 = x[(size_t)c1.x * 4 + f];
        acc = fmaf(v0, __int_as_float(c0.y), acc);
        acc = fmaf(v1, __int_as_float(c1.y), acc);
    }
    if (e < end) {
        int2 c = cp[e];
        acc = fmaf(x[(size_t)c.x * 4 + f], __int_as_float(c.y), acc);
    }
    float di = dis[node];
    acc = fmaf(x[(size_t)node * 4 + f], di * di, acc);
    xa[(size_t)node * 4 + f] = acc;
}

// h1 = relu(xa @ W1 + b1), stored fp16
__global__ void h1_k(const float* __restrict__ xa, const float* __restrict__ W1,
                     const float* __restrict__ b1, __half* __restrict__ h1, int N) {
    int gid = blockIdx.x * 256 + threadIdx.x;
    if (gid >= N * HDIM) return;
    int i = gid >> 6, f = gid & 63;
    float4 v = *(const float4*)(xa + (size_t)i * 4);
    float acc = b1[f];
    acc = fmaf(v.x, W1[f], acc);
    acc = fmaf(v.y, W1[64 + f], acc);
    acc = fmaf(v.z, W1[128 + f], acc);
    acc = fmaf(v.w, W1[192 + f], acc);
    h1[gid] = __float2half(fmaxf(acc, 0.f));
}

// ---------------- Layer 2: aggregate fp16 h1 (2 edges/wave, 2-deep) ----------
// g[i] = sum_e norm_e * h1[src_e] + dis_i^2 * h1[i]   (fp16 out, fp32 accum)
__global__ void __launch_bounds__(256) agg2_k(
    const __half* __restrict__ h1, __half* __restrict__ g,
    const int* __restrict__ rowptr, const int2* __restrict__ cp,
    const float* __restrict__ dis, int N) {
    int wid = threadIdx.x >> 6, lane = threadIdx.x & 63;
    int i = blockIdx.x * 4 + wid;
    if (i >= N) return;
    int beg = rowptr[i], end = rowptr[i + 1];
    int side = lane >> 5, lh = lane & 31;   // lanes 0-31: edge e; 32-63: edge e+1
    float ax = 0.f, ay = 0.f;
    int e = beg;
    for (; e + 4 <= end; e += 4) {          // 2 edges/side x 2 unroll = 4 in flight
        int2 c0 = cp[e + side];
        int2 c1 = cp[e + 2 + side];
        __half2 v0 = *(const __half2*)(h1 + (size_t)c0.x * HDIM + lh * 2);
        __half2 v1 = *(const __half2*)(h1 + (size_t)c1.x * HDIM + lh * 2);
        float2 f0 = __half22float2(v0), f1 = __half22float2(v1);
        float n0 = __int_as_float(c0.y), n1 = __int_as_float(c1.y);
        ax = fmaf(f0.x, n0, ax); ay = fmaf(f0.y, n0, ay);
        ax = fmaf(f1.x, n1, ax); ay = fmaf(f1.y, n1, ay);
    }
    if (e + 2 <= end) {
        int2 c = cp[e + side];
        __half2 v = *(const __half2*)(h1 + (size_t)c.x * HDIM + lh * 2);
        float2 f0 = __half22float2(v);
        float n0 = __int_as_float(c.y);
        ax = fmaf(f0.x, n0, ax); ay = fmaf(f0.y, n0, ay);
        e += 2;
    }
    if (e < end && side == 0) {             // odd remainder: side 0 only
        int2 c = cp[e];
        __half2 v = *(const __half2*)(h1 + (size_t)c.x * HDIM + lh * 2);
        float2 f0 = __half22float2(v);
        float n0 = __int_as_float(c.y);
        ax = fmaf(f0.x, n0, ax); ay = fmaf(f0.y, n0, ay);
    }
    ax += __shfl_xor(ax, 32, 64);           // combine the two edge-sides
    ay += __shfl_xor(ay, 32, 64);
    if (side == 0) {
        float di = dis[i];
        __half2 hv = *(const __half2*)(h1 + (size_t)i * HDIM + lh * 2);
        float2 hf = __half22float2(hv);
        ax = fmaf(hf.x, di * di, ax);
        ay = fmaf(hf.y, di * di, ay);
        *(__half2*)(g + (size_t)i * HDIM + lh * 2) = __floats2half2_rn(ax, ay);
    }
}

// h2 = relu(g @ W2 + b2), fp32 out; W2 staged in LDS
__global__ void gemm64b_k(const __half* __restrict__ gin, const float* __restrict__ W2,
                          const float* __restrict__ b2, float* __restrict__ h2, int N) {
    __shared__ float w[64 * 64];
    int t = threadIdx.x;
    for (int j = t; j < 64 * 64; j += 256) w[j] = W2[j];
    __syncthreads();
    int gid = blockIdx.x * 256 + t;
    if (gid >= N * HDIM) return;
    int i = gid >> 6, f = gid & 63;
    const __half2* hr = (const __half2*)(gin + (size_t)i * HDIM);
    float acc = 0.f;
    #pragma unroll 8
    for (int k = 0; k < 32; k++) {
        float2 hv = __half22float2(hr[k]);     // wave-uniform broadcast
        acc = fmaf(hv.x, w[(2 * k) * 64 + f], acc);
        acc = fmaf(hv.y, w[(2 * k + 1) * 64 + f], acc);
    }
    h2[gid] = fmaxf(acc + b2[f], 0.f);
}

// P = h2@Wm1[0:64]+bm1, Q = h2@Wm1[64:128]  (fp16)
__global__ void pq_k(const float* __restrict__ h, const float* __restrict__ Wm1,
                     const float* __restrict__ bm1,
                     __half* __restrict__ Ph, __half* __restrict__ Qh, int N) {
    __shared__ float w[128 * 64];     // 32 KB
    int t = threadIdx.x;
    for (int j = t; j < 128 * 64; j += 256) w[j] = Wm1[j];
    __syncthreads();
    int gid = blockIdx.x * 256 + t;
    if (gid >= N * HDIM) return;
    int i = gid >> 6, f = gid & 63;
    const float* hr = h + (size_t)i * HDIM;
    float a = bm1[f], b = 0.f;
    #pragma unroll 8
    for (int k = 0; k < 64; k++) {
        float hv = hr[k];             // wave-uniform broadcast
        a = fmaf(hv, w[k * 64 + f], a);
        b = fmaf(hv, w[(64 + k) * 64 + f], b);
    }
    Ph[gid] = __float2half(a);
    Qh[gid] = __float2half(b);
}

// ---------------- Edge finalize: 2 edges per 8-lane group ----------------
__device__ __forceinline__ float mlp8(uint4 pv, uint4 qv, float4 eav,
                                      const float wer[4][8], const float w2r[8]) {
    float p = 0.f;
    #pragma unroll
    for (int w = 0; w < 4; w++) {
        unsigned pu = (&pv.x)[w], qu = (&qv.x)[w];
        float2 pf = __half22float2(__builtin_bit_cast(__half2, pu));
        float2 qf = __half22float2(__builtin_bit_cast(__half2, qu));
        int j0 = 2 * w, j1 = 2 * w + 1;
        float z0 = pf.x + qf.x;
        z0 = fmaf(eav.x, wer[0][j0], z0); z0 = fmaf(eav.y, wer[1][j0], z0);
        z0 = fmaf(eav.z, wer[2][j0], z0); z0 = fmaf(eav.w, wer[3][j0], z0);
        float z1 = pf.y + qf.y;
        z1 = fmaf(eav.x, wer[0][j1], z1); z1 = fmaf(eav.y, wer[1][j1], z1);
        z1 = fmaf(eav.z, wer[2][j1], z1); z1 = fmaf(eav.w, wer[3][j1], z1);
        p = fmaf(fmaxf(z0, 0.f), w2r[j0], p);
        p = fmaf(fmaxf(z1, 0.f), w2r[j1], p);
    }
    return p;
}

__global__ void __launch_bounds__(256) edgefin_k(
    const int* __restrict__ src, const int* __restrict__ dst,
    const float* __restrict__ ea,
    const __half* __restrict__ Ph, const __half* __restrict__ Qh,
    const float* __restrict__ Wm1, const float* __restrict__ Wm2,
    const float* __restrict__ bm2, float* __restrict__ out, int E) {
    int q = threadIdx.x & 7;
    int fb = q * 8;
    float w2r[8];
    float wer[4][8];
    *(float4*)&w2r[0] = *(const float4*)(Wm2 + fb);
    *(float4*)&w2r[4] = *(const float4*)(Wm2 + fb + 4);
    #pragma unroll
    for (int r = 0; r < 4; r++) {
        *(float4*)&wer[r][0] = *(const float4*)(Wm1 + (128 + r) * 64 + fb);
        *(float4*)&wer[r][4] = *(const float4*)(Wm1 + (128 + r) * 64 + fb + 4);
    }
    float b2v = bm2[0];

    int base = blockIdx.x * 64 + (threadIdx.x >> 3);   // 64 edges per block pass
    int gstride = gridDim.x * 64;
    for (int e1 = base; e1 < E; e1 += gstride) {
        int e2 = e1 + 32; int e2c = (e2 < E) ? e2 : (E - 1);
        int s1 = src[e1], d1 = dst[e1];
        int s2 = src[e2c], d2 = dst[e2c];
        uint4 pv1 = *(const uint4*)((const unsigned short*)Ph + (size_t)s1 * HDIM + fb);
        uint4 qv1 = *(const uint4*)((const unsigned short*)Qh + (size_t)d1 * HDIM + fb);
        uint4 pv2 = *(const uint4*)((const unsigned short*)Ph + (size_t)s2 * HDIM + fb);
        uint4 qv2 = *(const uint4*)((const unsigned short*)Qh + (size_t)d2 * HDIM + fb);
        float4 ea1 = *(const float4*)(ea + (size_t)e1 * 4);
        float4 ea2 = *(const float4*)(ea + (size_t)e2c * 4);
        float p1 = mlp8(pv1, qv1, ea1, wer, w2r);
        float p2 = mlp8(pv2, qv2, ea2, wer, w2r);
        p1 += __shfl_xor(p1, 1, 64); p1 += __shfl_xor(p1, 2, 64); p1 += __shfl_xor(p1, 4, 64);
        p2 += __shfl_xor(p2, 1, 64); p2 += __shfl_xor(p2, 2, 64); p2 += __shfl_xor(p2, 4, 64);
        if (q == 0) {
            out[e1] = p1 + b2v;
            if (e2 < E) out[e2] = p2 + b2v;
        }
    }
}

extern "C" void kernel_launch(void* const* d_in, const int* in_sizes, int n_in,
                              void* d_out, int out_size, void* d_ws, size_t ws_size,
                              hipStream_t stream) {
    const float* x   = (const float*)d_in[0];
    const int*   ei  = (const int*)d_in[1];
    const float* ea  = (const float*)d_in[2];
    const float* W1  = (const float*)d_in[3];
    const float* b1  = (const float*)d_in[4];
    const float* W2  = (const float*)d_in[5];
    const float* b2  = (const float*)d_in[6];
    const float* Wm1 = (const float*)d_in[7];
    const float* bm1 = (const float*)d_in[8];
    const float* Wm2 = (const float*)d_in[9];
    const float* bm2 = (const float*)d_in[10];
    float* out = (float*)d_out;

    int N = in_sizes[0] / 4;    // 100000
    int E = in_sizes[1] / 2;    // 3200000
    const int* src = ei;
    const int* dst = ei + E;

    char* wp = (char*)d_ws;
    auto carve = [&](size_t bytes) -> void* {
        void* p = (void*)wp;
        wp += (bytes + 255) & ~(size_t)255;
        return p;
    };
    int*   cnt    = (int*)carve((size_t)N * 4);
    int*   rowptr = (int*)carve((size_t)(N + 1) * 4);
    int*   fillc  = (int*)carve((size_t)N * 4);
    float* dis    = (float*)carve((size_t)N * 4);
    int*   bsum   = (int*)carve(1024 * 4);
    int2*  cpack  = (int2*)carve((size_t)E * 8);
    // S1: fp32 N*64 (xa uses first 1.6MB; later h2). S2: fp16 N*64 (h1; later Qh).
    // S3: fp16 N*64 (g; later Ph). Total ~78.4MB = proven R5 footprint.
    float*  S1 = (float*)carve((size_t)N * HDIM * 4);
    __half* S2 = (__half*)carve((size_t)N * HDIM * 2);
    __half* S3 = (__half*)carve((size_t)N * HDIM * 2);
    float*  xa = S1;
    __half* h1 = S2;
    __half* g  = S3;
    float*  h2 = S1;      // xa dead after h1_k
    __half* Ph = S3;      // g dead after gemm64b_k
    __half* Qh = S2;      // h1 dead after agg2_k

    hipMemsetAsync(cnt, 0, (size_t)N * 4, stream);
    hipMemsetAsync(fillc, 0, (size_t)N * 4, stream);

    int eb = (E + 255) / 256;
    int sb = (N + 1023) / 1024;

    count_k<<<eb, 256, 0, stream>>>(dst, cnt, E);
    dis_k<<<(N + 255) / 256, 256, 0, stream>>>(cnt, dis, N);
    scan1_k<<<sb, 256, 0, stream>>>(cnt, rowptr, bsum, N);
    scan2_k<<<1, 256, 0, stream>>>(bsum, sb);
    scan3_k<<<sb, 256, 0, stream>>>(rowptr, bsum, N, E);
    fill_k<<<eb, 256, 0, stream>>>(src, dst, rowptr, fillc, dis, cpack, E);

    aggX_k<<<(N + 63) / 64, 256, 0, stream>>>(x, xa, rowptr, cpack, dis, N);
    h1_k<<<(N * HDIM + 255) / 256, 256, 0, stream>>>(xa, W1, b1, h1, N);
    agg2_k<<<(N + 3) / 4, 256, 0, stream>>>(h1, g, rowptr, cpack, dis, N);
    gemm64b_k<<<(N * HDIM + 255) / 256, 256, 0, stream>>>(g, W2, b2, h2, N);
    pq_k<<<(N * HDIM + 255) / 256, 256, 0, stream>>>(h2, Wm1, bm1, Ph, Qh, N);
    edgefin_k<<<2048, 256, 0, stream>>>(src, dst, ea, Ph, Qh, Wm1, Wm2, bm2, out, E);
}